// Round 10
// baseline (441.251 us; speedup 1.0000x reference)
//
#include <hip/hip_runtime.h>

typedef unsigned short u16;
typedef unsigned char u8;
typedef unsigned int u32;
typedef __attribute__((ext_vector_type(8))) short short8;  // 8 bf16 (4 VGPRs) MFMA A/B frag
typedef __attribute__((ext_vector_type(4))) short short4v; // 4 bf16 (8B)
typedef __attribute__((ext_vector_type(4))) float f32x4;   // MFMA C/D frag
typedef __attribute__((ext_vector_type(2))) float f32x2;   // packed-f32 pair (v_pk_* ops)
typedef __attribute__((ext_vector_type(4))) u32 u32x4;

#define L_ROWS 200000
#define TM 64
#define LDP 136   // 128 + 8 bf16 pad
#define NWH 16384 // Wh element count (128x128)
#define NWG 32768 // Wg element count (128x256)

__device__ __forceinline__ float b2f(u16 u) {
  union { u32 i; float f; } v; v.i = ((u32)u) << 16; return v.f;
}
__device__ __forceinline__ u16 f2b(float f) {  // RNE f32 -> bf16
  union { float fv; u32 i; } v; v.fv = f;
  return (u16)((v.i + 0x7fffu + ((v.i >> 16) & 1u)) >> 16);
}
// pack 4 f32 -> 4 e4m3 bytes in one u32 (HW RNE, OCP on gfx950)
__device__ __forceinline__ u32 pk4_fp8(float f0, float f1, float f2, float f3) {
  u32 w = __builtin_amdgcn_cvt_pk_fp8_f32(f0, f1, 0, false);
  w = __builtin_amdgcn_cvt_pk_fp8_f32(f2, f3, w, true);
  return w;
}

// ---- kernel W: one-time f32 -> bf16 weight conversion (WB = WhB[16384] | WgB[32768]) ----
__global__ __launch_bounds__(256) void kW(const float* __restrict__ Wh,
                                          const float* __restrict__ Wg,
                                          u16* __restrict__ WB) {
  int i = blockIdx.x * 256 + threadIdx.x;
  if (i < NWH) WB[i] = f2b(Wh[i]);
  else WB[i] = f2b(Wg[i - NWH]);
}

// ---- kernel A (UNCHANGED from round 8/9): H = relu(X@Wh^T+bh); U0 = H@Wg0^T;
//      U1 = H@Wg1^T + bg (bias folded). Idempotent when U buffers don't alias X. ----
__global__ __launch_bounds__(256) void kA(const float* X,
                                          const float* bh,
                                          const float* bg,
                                          const u16* __restrict__ WB,
                                          u16* U0b, int strideB,          // u16 elems/row
                                          u8* F0, u8* F1, int strideF) {  // bytes/row
  __shared__ u16 tileA[TM][LDP];  // X tile -> H tile -> U0 staging
  __shared__ u16 tileB[TM][LDP];  // U1 staging
  const int b = blockIdx.x, t = threadIdx.x;
  const int wave = t >> 6, lane = t & 63;
  const int ln = lane & 15, quad = lane >> 4;
  const u16* WhB = WB;
  const u16* WgB = WB + NWH;

  {  // stage X tile 64x128 f32 -> bf16 LDS; coalesced float4 loads
    const float* src = X + (size_t)b * TM * 128;
#pragma unroll
    for (int i = 0; i < 8; i++) {
      int e = t * 4 + i * 1024;
      float4 v = *(const float4*)(src + e);
      u16 pk[4] = { f2b(v.x), f2b(v.y), f2b(v.z), f2b(v.w) };
      *(short4v*)&tileA[e >> 7][e & 127] = *(const short4v*)pk;
    }
  }

  __syncthreads();

  // GEMM1 (H = X @ Wh^T): wave covers H cols [wave*32, wave*32+32)
  f32x4 acc1[4][2] = {};
#pragma unroll
  for (int ks = 0; ks < 4; ks++) {
    short8 bf1[2];
#pragma unroll
    for (int nt = 0; nt < 2; nt++) {
      int n = wave * 32 + nt * 16 + ln;
      bf1[nt] = *(const short8*)(WhB + n * 128 + ks * 32 + quad * 8);
    }
    short8 af[4];
#pragma unroll
    for (int mt = 0; mt < 4; mt++) af[mt] = *(const short8*)&tileA[mt * 16 + ln][ks * 32 + quad * 8];
#pragma unroll
    for (int mt = 0; mt < 4; mt++)
#pragma unroll
      for (int nt = 0; nt < 2; nt++)
        acc1[mt][nt] = __builtin_amdgcn_mfma_f32_16x16x32_bf16(af[mt], bf1[nt], acc1[mt][nt], 0, 0, 0);
  }

  __syncthreads();  // X reads complete before H overwrite

  // H = relu(acc1 + bh) -> tileA. D layout: col(n)=ln, row(m)=quad*4+reg
#pragma unroll
  for (int nt = 0; nt < 2; nt++) {
    int n = wave * 32 + nt * 16 + ln;
    float bias = bh[n];
#pragma unroll
    for (int r = 0; r < 4; r++)
#pragma unroll
      for (int mt = 0; mt < 4; mt++)
        tileA[mt * 16 + quad * 4 + r][n] = f2b(fmaxf(acc1[mt][nt][r] + bias, 0.f));
  }

  __syncthreads();

  // GEMM2, N=256: wave w owns cols n = w*64 + nt*16 + ln (waves 0-1 -> U0, 2-3 -> U1)
  f32x4 acc2[4][4] = {};
#pragma unroll
  for (int ks = 0; ks < 4; ks++) {
    short8 bf2[4];
#pragma unroll
    for (int nt = 0; nt < 4; nt++) {
      int n = wave * 64 + nt * 16 + ln;
      const u16* base = (n < 128) ? (WgB + n * 256) : (WgB + (n - 128) * 256 + 128);
      bf2[nt] = *(const short8*)(base + ks * 32 + quad * 8);
    }
    short8 af[4];
#pragma unroll
    for (int mt = 0; mt < 4; mt++) af[mt] = *(const short8*)&tileA[mt * 16 + ln][ks * 32 + quad * 8];
#pragma unroll
    for (int mt = 0; mt < 4; mt++)
#pragma unroll
      for (int nt = 0; nt < 4; nt++)
        acc2[mt][nt] = __builtin_amdgcn_mfma_f32_16x16x32_bf16(af[mt], bf2[nt], acc2[mt][nt], 0, 0, 0);
  }

  __syncthreads();  // H reads complete before tileA reuse

  // single staging pass: waves 0-1 stage U0 -> tileA; waves 2-3 stage U1+bg -> tileB
  if (wave < 2) {
#pragma unroll
    for (int nt = 0; nt < 4; nt++) {
      int n = wave * 64 + nt * 16 + ln;
#pragma unroll
      for (int mt = 0; mt < 4; mt++)
#pragma unroll
        for (int r = 0; r < 4; r++)
          tileA[mt * 16 + quad * 4 + r][n] = f2b(acc2[mt][nt][r]);
    }
  } else {
#pragma unroll
    for (int nt = 0; nt < 4; nt++) {
      int n = wave * 64 + nt * 16 + ln - 128;
      float bias = bg[n];
#pragma unroll
      for (int mt = 0; mt < 4; mt++)
#pragma unroll
        for (int r = 0; r < 4; r++)
          tileB[mt * 16 + quad * 4 + r][n] = f2b(acc2[mt][nt][r] + bias);
    }
  }
  __syncthreads();

  // stores: thread handles row rr, 32-col chunk cs
  {
    const int rr = t >> 2, cs = (t & 3) * 32;
    const size_t row = (size_t)b * TM + rr;
    u16* dstB = U0b + row * strideB + cs;
    u8* dstF0 = F0 + row * strideF + cs;
    u8* dstF1 = F1 + row * strideF + cs;
    u32 w0[8], w1[8];
#pragma unroll
    for (int c = 0; c < 4; c++) {
      short8 v = *(const short8*)&tileA[rr][cs + c * 8];
      *(short8*)(dstB + c * 8) = v;
      w0[c * 2 + 0] = pk4_fp8(b2f((u16)v[0]), b2f((u16)v[1]), b2f((u16)v[2]), b2f((u16)v[3]));
      w0[c * 2 + 1] = pk4_fp8(b2f((u16)v[4]), b2f((u16)v[5]), b2f((u16)v[6]), b2f((u16)v[7]));
      short8 u = *(const short8*)&tileB[rr][cs + c * 8];
      w1[c * 2 + 0] = pk4_fp8(b2f((u16)u[0]), b2f((u16)u[1]), b2f((u16)u[2]), b2f((u16)u[3]));
      w1[c * 2 + 1] = pk4_fp8(b2f((u16)u[4]), b2f((u16)u[5]), b2f((u16)u[6]), b2f((u16)u[7]));
    }
    *(u32x4*)dstF0 = u32x4{w0[0], w0[1], w0[2], w0[3]};
    *(u32x4*)(dstF0 + 16) = u32x4{w0[4], w0[5], w0[6], w0[7]};
    *(u32x4*)dstF1 = u32x4{w1[0], w1[1], w1[2], w1[3]};
    *(u32x4*)(dstF1 + 16) = u32x4{w1[4], w1[5], w1[6], w1[7]};
  }
}

// ---- kernel BC (BYTE-IDENTICAL to round 9 for clean attribution) ----
__global__ __launch_bounds__(256) void kBC(const int* __restrict__ perm,
                                           const u16* __restrict__ U0b, int strideB,
                                           const u8* __restrict__ F0,
                                           const u8* __restrict__ F1, int strideF,
                                           const u16* __restrict__ WB,
                                           const float* __restrict__ bg,
                                           const float* __restrict__ Wf,
                                           const float* __restrict__ bfs,
                                           float* __restrict__ out) {
  __shared__ u16 Elds[TM][LDP];
  __shared__ float outacc[TM];
  __shared__ int2 sidx[TM][17];  // 17: bank-spread
  const int b = blockIdx.x, t = threadIdx.x;
  const int wave = t >> 6, lane = t & 63;
  const int ln = lane & 15, quad = lane >> 4;
  const u16* WgB = WB + NWH;

  if (t < TM) {
    outacc[t] = 0.f;
    // sort this row's 16 (i0,i1) pairs by i0 (Batcher odd-even mergesort, 63 CEs)
    const int* pr = perm + ((size_t)b * TM + t) * 32;
    int k0[16], k1[16];
#pragma unroll
    for (int s = 0; s < 16; s++) { k0[s] = pr[s]; k1[s] = pr[16 + s]; }
#define CE(a, bq) { int ka = k0[a], kb = k0[bq]; bool sw = ka > kb;                    \
                    k0[a] = sw ? kb : ka; k0[bq] = sw ? ka : kb;                       \
                    int pa = k1[a], pb = k1[bq];                                       \
                    k1[a] = sw ? pb : pa; k1[bq] = sw ? pa : pb; }
    CE(0,1) CE(2,3) CE(4,5) CE(6,7) CE(8,9) CE(10,11) CE(12,13) CE(14,15)
    CE(0,2) CE(1,3) CE(4,6) CE(5,7) CE(8,10) CE(9,11) CE(12,14) CE(13,15)
    CE(1,2) CE(5,6) CE(9,10) CE(13,14)
    CE(0,4) CE(1,5) CE(2,6) CE(3,7) CE(8,12) CE(9,13) CE(10,14) CE(11,15)
    CE(2,4) CE(3,5) CE(10,12) CE(11,13)
    CE(1,2) CE(3,4) CE(5,6) CE(9,10) CE(11,12) CE(13,14)
    CE(0,8) CE(1,9) CE(2,10) CE(3,11) CE(4,12) CE(5,13) CE(6,14) CE(7,15)
    CE(4,8) CE(5,9) CE(6,10) CE(7,11)
    CE(2,4) CE(3,5) CE(6,8) CE(7,9) CE(10,12) CE(11,13)
    CE(1,2) CE(3,4) CE(5,6) CE(7,8) CE(9,10) CE(11,12) CE(13,14)
#undef CE
#pragma unroll
    for (int s = 0; s < 16; s++) sidx[t][s] = make_int2(k0[s], k1[s]);
  }
  __syncthreads();

  // phase 1: fp8 gather-accumulate, 4 threads/row, 32 cols each.
  const int r = t >> 2, cq = (t & 3) * 32;

  f32x2 acc[16] = {};
  const f32x2 zero2 = {0.f, 0.f};
#pragma unroll
  for (int sb = 0; sb < 16; sb += 4) {
    u32x4 A0[4], A1[4], C0[4], C1[4];
#pragma unroll
    for (int k = 0; k < 4; k++) {
      int2 pr = sidx[r][sb + k];  // broadcast to the 4 threads of this row
      const u8* r0 = F0 + (size_t)pr.x * strideF + cq;
      const u8* r1 = F1 + (size_t)pr.y * strideF + cq;
      A0[k] = *(const u32x4*)r0; A1[k] = *(const u32x4*)(r0 + 16);
      C0[k] = *(const u32x4*)r1; C1[k] = *(const u32x4*)(r1 + 16);
    }
#pragma unroll
    for (int k = 0; k < 4; k++) {
#pragma unroll
      for (int w = 0; w < 4; w++) {
        f32x2 va0 = __builtin_amdgcn_cvt_pk_f32_fp8(A0[k][w], false);
        f32x2 va1 = __builtin_amdgcn_cvt_pk_f32_fp8(A0[k][w], true);
        f32x2 vc0 = __builtin_amdgcn_cvt_pk_f32_fp8(C0[k][w], false);
        f32x2 vc1 = __builtin_amdgcn_cvt_pk_f32_fp8(C0[k][w], true);
        acc[2 * w]     += __builtin_elementwise_max(va0 + vc0, zero2);
        acc[2 * w + 1] += __builtin_elementwise_max(va1 + vc1, zero2);
        f32x2 ua0 = __builtin_amdgcn_cvt_pk_f32_fp8(A1[k][w], false);
        f32x2 ua1 = __builtin_amdgcn_cvt_pk_f32_fp8(A1[k][w], true);
        f32x2 uc0 = __builtin_amdgcn_cvt_pk_f32_fp8(C1[k][w], false);
        f32x2 uc1 = __builtin_amdgcn_cvt_pk_f32_fp8(C1[k][w], true);
        acc[8 + 2 * w]     += __builtin_elementwise_max(ua0 + uc0, zero2);
        acc[8 + 2 * w + 1] += __builtin_elementwise_max(ua1 + uc1, zero2);
      }
    }
  }

  // E = acc/16 (acc is a sum of relus, already >= 0) -> LDS bf16
#pragma unroll
  for (int j = 0; j < 4; j++) {
    u16 pk[8];
#pragma unroll
    for (int e = 0; e < 4; e++) {
      f32x2 v = acc[j * 4 + e];
      pk[e * 2]     = f2b(v[0] * 0.0625f);
      pk[e * 2 + 1] = f2b(v[1] * 0.0625f);
    }
    *(short8*)&Elds[r][cq + j * 8] = *(const short8*)pk;
  }

  __syncthreads();

  // phase 2: D = E @ Wg1^T; wave covers n in [wave*32, wave*32+32); bf16 weight frags
  short8 bw[2][4];
#pragma unroll
  for (int nt = 0; nt < 2; nt++) {
    int n = wave * 32 + nt * 16 + ln;
#pragma unroll
    for (int ks = 0; ks < 4; ks++)
      bw[nt][ks] = *(const short8*)(WgB + n * 256 + 128 + ks * 32 + quad * 8);
  }

  f32x4 d[4][2] = {};
#pragma unroll
  for (int ks = 0; ks < 4; ks++) {
    short8 af[4];
#pragma unroll
    for (int mt = 0; mt < 4; mt++) af[mt] = *(const short8*)&Elds[mt * 16 + ln][ks * 32 + quad * 8];
#pragma unroll
    for (int mt = 0; mt < 4; mt++)
#pragma unroll
      for (int nt = 0; nt < 2; nt++)
        d[mt][nt] = __builtin_amdgcn_mfma_f32_16x16x32_bf16(af[mt], bw[nt][ks], d[mt][nt], 0, 0, 0);
  }

  float wfv[2], bgv2[2];
  int ncol[2];
#pragma unroll
  for (int nt = 0; nt < 2; nt++) {
    ncol[nt] = wave * 32 + nt * 16 + ln;
    wfv[nt] = Wf[ncol[nt]];
    bgv2[nt] = bg[ncol[nt]];
  }

  // epilogue: E2 = relu(D + U0 + bg); dot with Wf; butterfly-reduce over 16 ln-lanes
#pragma unroll
  for (int mt = 0; mt < 4; mt++)
#pragma unroll
    for (int rr = 0; rr < 4; rr++) {
      int row = mt * 16 + quad * 4 + rr;
      size_t grow = (size_t)b * TM + row;
      float p = 0.f;
#pragma unroll
      for (int nt = 0; nt < 2; nt++) {
        float u0v = b2f(U0b[grow * strideB + ncol[nt]]);
        float e2 = fmaxf(d[mt][nt][rr] + u0v + bgv2[nt], 0.f);
        p += e2 * wfv[nt];
      }
      p += __shfl_xor(p, 1, 64);
      p += __shfl_xor(p, 2, 64);
      p += __shfl_xor(p, 4, 64);
      p += __shfl_xor(p, 8, 64);
      if (ln == 0) atomicAdd(&outacc[row], p);
    }

  __syncthreads();
  if (t < TM) out[(size_t)b * TM + t] = outacc[t] + bfs[0];
}

extern "C" void kernel_launch(void* const* d_in, const int* in_sizes, int n_in,
                              void* d_out, int out_size, void* d_ws, size_t ws_size,
                              hipStream_t stream) {
  const float* X  = (const float*)d_in[0];
  const int* perm = (const int*)d_in[1];
  const float* Wh = (const float*)d_in[2];
  const float* bh = (const float*)d_in[3];
  const float* Wg = (const float*)d_in[4];
  const float* bg = (const float*)d_in[5];
  const float* Wf = (const float*)d_in[6];
  const float* bf = (const float*)d_in[7];
  float* out = (float*)d_out;

  const size_t bfBytes = (size_t)L_ROWS * 128 * sizeof(u16);  // 51.2 MB
  const size_t f8Bytes = (size_t)L_ROWS * 128;                // 25.6 MB each
  const size_t wBytes  = (size_t)(NWH + NWG) * sizeof(u16);   // 96 KB

  u16* U0b; int strideB;
  u8 *F0, *F1; int strideF;
  u16* WB;
  bool wsBranch = (ws_size >= bfBytes + 2 * f8Bytes + wBytes);
  if (wsBranch) {
    // preferred: everything in workspace, inputs untouched
    U0b = (u16*)d_ws;                    strideB = 128;
    F0 = (u8*)d_ws + bfBytes;            F1 = F0 + f8Bytes;   strideF = 128;
    WB = (u16*)(F1 + f8Bytes);
  } else {
    // fallback: U in-place in X footprint (512 B/row: bf16U0 | fp8U0 | fp8U1)
    u8* base = (u8*)d_in[0];
    U0b = (u16*)base;                    strideB = 256;
    F0 = base + 256;                     F1 = base + 384;     strideF = 512;
    WB = (u16*)d_ws;
  }

  dim3 block(256);
  kW<<<dim3((NWH + NWG) / 256), block, 0, stream>>>(Wh, Wg, WB);
  kA<<<dim3(L_ROWS / TM), block, 0, stream>>>(X, bh, bg, WB, U0b, strideB, F0, F1, strideF);
  // R10 DIFFERENTIAL MEASUREMENT: second identical kA launch (idempotent in the ws
  // branch — reads only pristine X, rewrites identical U). total_r10 - total_r9 = kA
  // duration exactly. Skipped in the in-place branch (kA there consumes X).
  if (wsBranch)
    kA<<<dim3(L_ROWS / TM), block, 0, stream>>>(X, bh, bg, WB, U0b, strideB, F0, F1, strideF);
  kBC<<<dim3(L_ROWS / TM), block, 0, stream>>>(perm, U0b, strideB, F0, F1, strideF, WB, bg, Wf, bf, out);
}

// Round 11
// 350.457 us; speedup vs baseline: 1.2591x; 1.2591x over previous
//
#include <hip/hip_runtime.h>

typedef unsigned short u16;
typedef unsigned char u8;
typedef unsigned int u32;
typedef __attribute__((ext_vector_type(8))) short short8;  // 8 bf16 (4 VGPRs) MFMA A/B frag
typedef __attribute__((ext_vector_type(4))) short short4v; // 4 bf16 (8B)
typedef __attribute__((ext_vector_type(4))) float f32x4;   // MFMA C/D frag
typedef __attribute__((ext_vector_type(2))) float f32x2;   // packed-f32 pair (v_pk_* ops)
typedef __attribute__((ext_vector_type(4))) u32 u32x4;

#define L_ROWS 200000
#define TM 64
#define LDP 136   // 128 + 8 bf16 pad
#define NWH 16384 // Wh element count (128x128)
#define NWG 32768 // Wg element count (128x256)

__device__ __forceinline__ float b2f(u16 u) {
  union { u32 i; float f; } v; v.i = ((u32)u) << 16; return v.f;
}
__device__ __forceinline__ u16 f2b(float f) {  // RNE f32 -> bf16
  union { float fv; u32 i; } v; v.fv = f;
  return (u16)((v.i + 0x7fffu + ((v.i >> 16) & 1u)) >> 16);
}
// pack 4 f32 -> 4 e4m3 bytes in one u32 (HW RNE, OCP on gfx950)
__device__ __forceinline__ u32 pk4_fp8(float f0, float f1, float f2, float f3) {
  u32 w = __builtin_amdgcn_cvt_pk_fp8_f32(f0, f1, 0, false);
  w = __builtin_amdgcn_cvt_pk_fp8_f32(f2, f3, w, true);
  return w;
}

// ---- kernel W: one-time f32 -> bf16 weight conversion (WB = WhB[16384] | WgB[32768]) ----
__global__ __launch_bounds__(256) void kW(const float* __restrict__ Wh,
                                          const float* __restrict__ Wg,
                                          u16* __restrict__ WB) {
  int i = blockIdx.x * 256 + threadIdx.x;
  if (i < NWH) WB[i] = f2b(Wh[i]);
  else WB[i] = f2b(Wg[i - NWH]);
}

// ---- kernel A v2: H = relu(X@Wh^T+bh); U0 = H@Wg0^T; U1 = H@Wg1^T + bg ----
// GEMM2 split into two N=128 halves: acc peak 96 -> 64 VGPRs (higher occupancy),
// and U0/F0 stores issue before the U1 MFMA half so stores drain under compute.
// Per-column FP accumulation order identical to v1 -> bit-identical outputs.
__global__ __launch_bounds__(256) void kA(const float* X,
                                          const float* bh,
                                          const float* bg,
                                          const u16* __restrict__ WB,
                                          u16* U0b, int strideB,          // u16 elems/row
                                          u8* F0, u8* F1, int strideF) {  // bytes/row
  __shared__ u16 tileA[TM][LDP];  // X tile -> H tile
  __shared__ u16 tileB[TM][LDP];  // U0 staging, then U1 staging
  const int b = blockIdx.x, t = threadIdx.x;
  const int wave = t >> 6, lane = t & 63;
  const int ln = lane & 15, quad = lane >> 4;
  const u16* WhB = WB;
  const u16* WgB = WB + NWH;

  {  // stage X tile 64x128 f32 -> bf16 LDS; coalesced float4 loads
    const float* src = X + (size_t)b * TM * 128;
#pragma unroll
    for (int i = 0; i < 8; i++) {
      int e = t * 4 + i * 1024;
      float4 v = *(const float4*)(src + e);
      u16 pk[4] = { f2b(v.x), f2b(v.y), f2b(v.z), f2b(v.w) };
      *(short4v*)&tileA[e >> 7][e & 127] = *(const short4v*)pk;
    }
  }

  __syncthreads();

  // GEMM1 (H = X @ Wh^T): wave covers H cols [wave*32, wave*32+32)
  f32x4 acc1[4][2] = {};
#pragma unroll
  for (int ks = 0; ks < 4; ks++) {
    short8 bf1[2];
#pragma unroll
    for (int nt = 0; nt < 2; nt++) {
      int n = wave * 32 + nt * 16 + ln;
      bf1[nt] = *(const short8*)(WhB + n * 128 + ks * 32 + quad * 8);
    }
    short8 af[4];
#pragma unroll
    for (int mt = 0; mt < 4; mt++) af[mt] = *(const short8*)&tileA[mt * 16 + ln][ks * 32 + quad * 8];
#pragma unroll
    for (int mt = 0; mt < 4; mt++)
#pragma unroll
      for (int nt = 0; nt < 2; nt++)
        acc1[mt][nt] = __builtin_amdgcn_mfma_f32_16x16x32_bf16(af[mt], bf1[nt], acc1[mt][nt], 0, 0, 0);
  }

  __syncthreads();  // X reads complete before H overwrite

  // H = relu(acc1 + bh) -> tileA. D layout: col(n)=ln, row(m)=quad*4+reg
#pragma unroll
  for (int nt = 0; nt < 2; nt++) {
    int n = wave * 32 + nt * 16 + ln;
    float bias = bh[n];
#pragma unroll
    for (int r = 0; r < 4; r++)
#pragma unroll
      for (int mt = 0; mt < 4; mt++)
        tileA[mt * 16 + quad * 4 + r][n] = f2b(fmaxf(acc1[mt][nt][r] + bias, 0.f));
  }

  __syncthreads();

  // ---- GEMM2 half A: U0 cols. Wave covers n in [wave*32, wave*32+32). ----
  f32x4 acc2[4][2] = {};
#pragma unroll
  for (int ks = 0; ks < 4; ks++) {
    short8 bf2[2];
#pragma unroll
    for (int nt = 0; nt < 2; nt++) {
      int n = wave * 32 + nt * 16 + ln;
      bf2[nt] = *(const short8*)(WgB + n * 256 + ks * 32 + quad * 8);
    }
    short8 af[4];
#pragma unroll
    for (int mt = 0; mt < 4; mt++) af[mt] = *(const short8*)&tileA[mt * 16 + ln][ks * 32 + quad * 8];
#pragma unroll
    for (int mt = 0; mt < 4; mt++)
#pragma unroll
      for (int nt = 0; nt < 2; nt++)
        acc2[mt][nt] = __builtin_amdgcn_mfma_f32_16x16x32_bf16(af[mt], bf2[nt], acc2[mt][nt], 0, 0, 0);
  }

  // stage U0 -> tileB (all 4 waves, 128 cols)
#pragma unroll
  for (int nt = 0; nt < 2; nt++) {
    int n = wave * 32 + nt * 16 + ln;
#pragma unroll
    for (int mt = 0; mt < 4; mt++)
#pragma unroll
      for (int r = 0; r < 4; r++)
        tileB[mt * 16 + quad * 4 + r][n] = f2b(acc2[mt][nt][r]);
  }
  __syncthreads();

  // store U0b (bf16) + F0 (fp8) from tileB; issued BEFORE half B so they drain under MFMA
  {
    const int rr = t >> 2, cs = (t & 3) * 32;
    const size_t row = (size_t)b * TM + rr;
    u16* dstB = U0b + row * strideB + cs;
    u8* dstF0 = F0 + row * strideF + cs;
    u32 w0[8];
#pragma unroll
    for (int c = 0; c < 4; c++) {
      short8 v = *(const short8*)&tileB[rr][cs + c * 8];
      *(short8*)(dstB + c * 8) = v;
      w0[c * 2 + 0] = pk4_fp8(b2f((u16)v[0]), b2f((u16)v[1]), b2f((u16)v[2]), b2f((u16)v[3]));
      w0[c * 2 + 1] = pk4_fp8(b2f((u16)v[4]), b2f((u16)v[5]), b2f((u16)v[6]), b2f((u16)v[7]));
    }
    *(u32x4*)dstF0 = u32x4{w0[0], w0[1], w0[2], w0[3]};
    *(u32x4*)(dstF0 + 16) = u32x4{w0[4], w0[5], w0[6], w0[7]};
  }

  // ---- GEMM2 half B: U1 cols (weight cols 128..255). Reads tileA only. ----
  f32x4 acc3[4][2] = {};
#pragma unroll
  for (int ks = 0; ks < 4; ks++) {
    short8 bf2[2];
#pragma unroll
    for (int nt = 0; nt < 2; nt++) {
      int n = wave * 32 + nt * 16 + ln;
      bf2[nt] = *(const short8*)(WgB + n * 256 + 128 + ks * 32 + quad * 8);
    }
    short8 af[4];
#pragma unroll
    for (int mt = 0; mt < 4; mt++) af[mt] = *(const short8*)&tileA[mt * 16 + ln][ks * 32 + quad * 8];
#pragma unroll
    for (int mt = 0; mt < 4; mt++)
#pragma unroll
      for (int nt = 0; nt < 2; nt++)
        acc3[mt][nt] = __builtin_amdgcn_mfma_f32_16x16x32_bf16(af[mt], bf2[nt], acc3[mt][nt], 0, 0, 0);
  }

  __syncthreads();  // all tileB store-reads done before restaging

  // stage U1+bg -> tileB
#pragma unroll
  for (int nt = 0; nt < 2; nt++) {
    int n = wave * 32 + nt * 16 + ln;
    float bias = bg[n];
#pragma unroll
    for (int mt = 0; mt < 4; mt++)
#pragma unroll
      for (int r = 0; r < 4; r++)
        tileB[mt * 16 + quad * 4 + r][n] = f2b(acc3[mt][nt][r] + bias);
  }
  __syncthreads();

  // store F1 (fp8)
  {
    const int rr = t >> 2, cs = (t & 3) * 32;
    const size_t row = (size_t)b * TM + rr;
    u8* dstF1 = F1 + row * strideF + cs;
    u32 w1[8];
#pragma unroll
    for (int c = 0; c < 4; c++) {
      short8 u = *(const short8*)&tileB[rr][cs + c * 8];
      w1[c * 2 + 0] = pk4_fp8(b2f((u16)u[0]), b2f((u16)u[1]), b2f((u16)u[2]), b2f((u16)u[3]));
      w1[c * 2 + 1] = pk4_fp8(b2f((u16)u[4]), b2f((u16)u[5]), b2f((u16)u[6]), b2f((u16)u[7]));
    }
    *(u32x4*)dstF1 = u32x4{w1[0], w1[1], w1[2], w1[3]};
    *(u32x4*)(dstF1 + 16) = u32x4{w1[4], w1[5], w1[6], w1[7]};
  }
}

// ---- kernel BC (BYTE-IDENTICAL to round 9 for clean attribution) ----
__global__ __launch_bounds__(256) void kBC(const int* __restrict__ perm,
                                           const u16* __restrict__ U0b, int strideB,
                                           const u8* __restrict__ F0,
                                           const u8* __restrict__ F1, int strideF,
                                           const u16* __restrict__ WB,
                                           const float* __restrict__ bg,
                                           const float* __restrict__ Wf,
                                           const float* __restrict__ bfs,
                                           float* __restrict__ out) {
  __shared__ u16 Elds[TM][LDP];
  __shared__ float outacc[TM];
  __shared__ int2 sidx[TM][17];  // 17: bank-spread
  const int b = blockIdx.x, t = threadIdx.x;
  const int wave = t >> 6, lane = t & 63;
  const int ln = lane & 15, quad = lane >> 4;
  const u16* WgB = WB + NWH;

  if (t < TM) {
    outacc[t] = 0.f;
    // sort this row's 16 (i0,i1) pairs by i0 (Batcher odd-even mergesort, 63 CEs)
    const int* pr = perm + ((size_t)b * TM + t) * 32;
    int k0[16], k1[16];
#pragma unroll
    for (int s = 0; s < 16; s++) { k0[s] = pr[s]; k1[s] = pr[16 + s]; }
#define CE(a, bq) { int ka = k0[a], kb = k0[bq]; bool sw = ka > kb;                    \
                    k0[a] = sw ? kb : ka; k0[bq] = sw ? ka : kb;                       \
                    int pa = k1[a], pb = k1[bq];                                       \
                    k1[a] = sw ? pb : pa; k1[bq] = sw ? pa : pb; }
    CE(0,1) CE(2,3) CE(4,5) CE(6,7) CE(8,9) CE(10,11) CE(12,13) CE(14,15)
    CE(0,2) CE(1,3) CE(4,6) CE(5,7) CE(8,10) CE(9,11) CE(12,14) CE(13,15)
    CE(1,2) CE(5,6) CE(9,10) CE(13,14)
    CE(0,4) CE(1,5) CE(2,6) CE(3,7) CE(8,12) CE(9,13) CE(10,14) CE(11,15)
    CE(2,4) CE(3,5) CE(10,12) CE(11,13)
    CE(1,2) CE(3,4) CE(5,6) CE(9,10) CE(11,12) CE(13,14)
    CE(0,8) CE(1,9) CE(2,10) CE(3,11) CE(4,12) CE(5,13) CE(6,14) CE(7,15)
    CE(4,8) CE(5,9) CE(6,10) CE(7,11)
    CE(2,4) CE(3,5) CE(6,8) CE(7,9) CE(10,12) CE(11,13)
    CE(1,2) CE(3,4) CE(5,6) CE(7,8) CE(9,10) CE(11,12) CE(13,14)
#undef CE
#pragma unroll
    for (int s = 0; s < 16; s++) sidx[t][s] = make_int2(k0[s], k1[s]);
  }
  __syncthreads();

  // phase 1: fp8 gather-accumulate, 4 threads/row, 32 cols each.
  const int r = t >> 2, cq = (t & 3) * 32;

  f32x2 acc[16] = {};
  const f32x2 zero2 = {0.f, 0.f};
#pragma unroll
  for (int sb = 0; sb < 16; sb += 4) {
    u32x4 A0[4], A1[4], C0[4], C1[4];
#pragma unroll
    for (int k = 0; k < 4; k++) {
      int2 pr = sidx[r][sb + k];  // broadcast to the 4 threads of this row
      const u8* r0 = F0 + (size_t)pr.x * strideF + cq;
      const u8* r1 = F1 + (size_t)pr.y * strideF + cq;
      A0[k] = *(const u32x4*)r0; A1[k] = *(const u32x4*)(r0 + 16);
      C0[k] = *(const u32x4*)r1; C1[k] = *(const u32x4*)(r1 + 16);
    }
#pragma unroll
    for (int k = 0; k < 4; k++) {
#pragma unroll
      for (int w = 0; w < 4; w++) {
        f32x2 va0 = __builtin_amdgcn_cvt_pk_f32_fp8(A0[k][w], false);
        f32x2 va1 = __builtin_amdgcn_cvt_pk_f32_fp8(A0[k][w], true);
        f32x2 vc0 = __builtin_amdgcn_cvt_pk_f32_fp8(C0[k][w], false);
        f32x2 vc1 = __builtin_amdgcn_cvt_pk_f32_fp8(C0[k][w], true);
        acc[2 * w]     += __builtin_elementwise_max(va0 + vc0, zero2);
        acc[2 * w + 1] += __builtin_elementwise_max(va1 + vc1, zero2);
        f32x2 ua0 = __builtin_amdgcn_cvt_pk_f32_fp8(A1[k][w], false);
        f32x2 ua1 = __builtin_amdgcn_cvt_pk_f32_fp8(A1[k][w], true);
        f32x2 uc0 = __builtin_amdgcn_cvt_pk_f32_fp8(C1[k][w], false);
        f32x2 uc1 = __builtin_amdgcn_cvt_pk_f32_fp8(C1[k][w], true);
        acc[8 + 2 * w]     += __builtin_elementwise_max(ua0 + uc0, zero2);
        acc[8 + 2 * w + 1] += __builtin_elementwise_max(ua1 + uc1, zero2);
      }
    }
  }

  // E = acc/16 (acc is a sum of relus, already >= 0) -> LDS bf16
#pragma unroll
  for (int j = 0; j < 4; j++) {
    u16 pk[8];
#pragma unroll
    for (int e = 0; e < 4; e++) {
      f32x2 v = acc[j * 4 + e];
      pk[e * 2]     = f2b(v[0] * 0.0625f);
      pk[e * 2 + 1] = f2b(v[1] * 0.0625f);
    }
    *(short8*)&Elds[r][cq + j * 8] = *(const short8*)pk;
  }

  __syncthreads();

  // phase 2: D = E @ Wg1^T; wave covers n in [wave*32, wave*32+32); bf16 weight frags
  short8 bw[2][4];
#pragma unroll
  for (int nt = 0; nt < 2; nt++) {
    int n = wave * 32 + nt * 16 + ln;
#pragma unroll
    for (int ks = 0; ks < 4; ks++)
      bw[nt][ks] = *(const short8*)(WgB + n * 256 + 128 + ks * 32 + quad * 8);
  }

  f32x4 d[4][2] = {};
#pragma unroll
  for (int ks = 0; ks < 4; ks++) {
    short8 af[4];
#pragma unroll
    for (int mt = 0; mt < 4; mt++) af[mt] = *(const short8*)&Elds[mt * 16 + ln][ks * 32 + quad * 8];
#pragma unroll
    for (int mt = 0; mt < 4; mt++)
#pragma unroll
      for (int nt = 0; nt < 2; nt++)
        d[mt][nt] = __builtin_amdgcn_mfma_f32_16x16x32_bf16(af[mt], bw[nt][ks], d[mt][nt], 0, 0, 0);
  }

  float wfv[2], bgv2[2];
  int ncol[2];
#pragma unroll
  for (int nt = 0; nt < 2; nt++) {
    ncol[nt] = wave * 32 + nt * 16 + ln;
    wfv[nt] = Wf[ncol[nt]];
    bgv2[nt] = bg[ncol[nt]];
  }

  // epilogue: E2 = relu(D + U0 + bg); dot with Wf; butterfly-reduce over 16 ln-lanes
#pragma unroll
  for (int mt = 0; mt < 4; mt++)
#pragma unroll
    for (int rr = 0; rr < 4; rr++) {
      int row = mt * 16 + quad * 4 + rr;
      size_t grow = (size_t)b * TM + row;
      float p = 0.f;
#pragma unroll
      for (int nt = 0; nt < 2; nt++) {
        float u0v = b2f(U0b[grow * strideB + ncol[nt]]);
        float e2 = fmaxf(d[mt][nt][rr] + u0v + bgv2[nt], 0.f);
        p += e2 * wfv[nt];
      }
      p += __shfl_xor(p, 1, 64);
      p += __shfl_xor(p, 2, 64);
      p += __shfl_xor(p, 4, 64);
      p += __shfl_xor(p, 8, 64);
      if (ln == 0) atomicAdd(&outacc[row], p);
    }

  __syncthreads();
  if (t < TM) out[(size_t)b * TM + t] = outacc[t] + bfs[0];
}

extern "C" void kernel_launch(void* const* d_in, const int* in_sizes, int n_in,
                              void* d_out, int out_size, void* d_ws, size_t ws_size,
                              hipStream_t stream) {
  const float* X  = (const float*)d_in[0];
  const int* perm = (const int*)d_in[1];
  const float* Wh = (const float*)d_in[2];
  const float* bh = (const float*)d_in[3];
  const float* Wg = (const float*)d_in[4];
  const float* bg = (const float*)d_in[5];
  const float* Wf = (const float*)d_in[6];
  const float* bf = (const float*)d_in[7];
  float* out = (float*)d_out;

  const size_t bfBytes = (size_t)L_ROWS * 128 * sizeof(u16);  // 51.2 MB
  const size_t f8Bytes = (size_t)L_ROWS * 128;                // 25.6 MB each
  const size_t wBytes  = (size_t)(NWH + NWG) * sizeof(u16);   // 96 KB

  u16* U0b; int strideB;
  u8 *F0, *F1; int strideF;
  u16* WB;
  if (ws_size >= bfBytes + 2 * f8Bytes + wBytes) {
    // preferred: everything in workspace, inputs untouched (confirmed live branch, r10)
    U0b = (u16*)d_ws;                    strideB = 128;
    F0 = (u8*)d_ws + bfBytes;            F1 = F0 + f8Bytes;   strideF = 128;
    WB = (u16*)(F1 + f8Bytes);
  } else {
    // fallback: U in-place in X footprint (512 B/row: bf16U0 | fp8U0 | fp8U1)
    u8* base = (u8*)d_in[0];
    U0b = (u16*)base;                    strideB = 256;
    F0 = base + 256;                     F1 = base + 384;     strideF = 512;
    WB = (u16*)d_ws;
  }

  dim3 block(256);
  kW<<<dim3((NWH + NWG) / 256), block, 0, stream>>>(Wh, Wg, WB);
  kA<<<dim3(L_ROWS / TM), block, 0, stream>>>(X, bh, bg, WB, U0b, strideB, F0, F1, strideF);
  kBC<<<dim3(L_ROWS / TM), block, 0, stream>>>(perm, U0b, strideB, F0, F1, strideF, WB, bg, Wf, bf, out);
}